// Round 1
// baseline (4783.660 us; speedup 1.0000x reference)
//
#include <hip/hip_runtime.h>
#include <math.h>

#define L_  1024
#define B_  2
#define D_  1024
#define H_  16
#define DH_ 64
#define M_  1024
#define T_  2048
#define SCALE_ 0.125f
// valid key j for query i: j <= i + M_

// ---------------------------------------------------------------------------
// Generic tiled fp32 GEMM  C[M,N] = A[M,K] @ W[K,N]  with flexible A source and
// epilogue scatter. K is always D_=1024. BM=BN=64, BK=16, 256 thr, 4x4/thread.
// amode 0: A rows linear; rows < splitRow come from A0, rest from A1 (concat).
// amode 1: A gathered from Ovec [B,H,L,DH]  (row=(l*B+b), col=h*64+d).
// omode 0: q -> outA=q+bu, outB=q+bv, layout [B,H,L,DH]
// omode 1: kv -> n<1024: k->outA else v->outB, layout [B,H,T,DH]
// omode 2: r -> outA layout [B,H,T,DH]
// omode 3: outA[m*D+n] = acc + resid[m*D+n]
// ---------------------------------------------------------------------------
__global__ __launch_bounds__(256) void gemm_proj(
    const float* __restrict__ A0, const float* __restrict__ A1, int splitRow,
    const float* __restrict__ W, int N,
    int amode, int omode,
    const float* __restrict__ bu, const float* __restrict__ bv,
    float* __restrict__ outA, float* __restrict__ outB,
    const float* __restrict__ resid)
{
    const int K = D_;
    __shared__ float As[16][68];   // stored transposed: As[k][m]
    __shared__ float Ws[16][68];

    int tid = threadIdx.x;
    int m0 = blockIdx.x * 64;
    int n0 = blockIdx.y * 64;
    int tm = tid >> 4;             // 0..15
    int tn = tid & 15;             // 0..15
    int lr  = tid >> 2;            // 0..63  A row within tile
    int lc4 = (tid & 3) << 2;      // 0,4,8,12
    int wr  = tid >> 4;            // 0..15  W row within tile
    int wc4 = (tid & 15) << 2;     // 0..60

    float acc[4][4];
    #pragma unroll
    for (int i = 0; i < 4; ++i)
        #pragma unroll
        for (int j = 0; j < 4; ++j) acc[i][j] = 0.f;

    for (int k0 = 0; k0 < K; k0 += 16) {
        int row = m0 + lr;
        float4 av;
        if (amode == 0) {
            const float* Ap = (row < splitRow) ? (A0 + (size_t)row * K)
                                               : (A1 + (size_t)(row - splitRow) * K);
            av = *(const float4*)(Ap + k0 + lc4);
        } else {
            int l = row / B_, b = row % B_;
            int col = k0 + lc4;
            int h = col >> 6, d = col & 63;
            av = *(const float4*)(A0 + (((size_t)(b * H_ + h)) * L_ + l) * DH_ + d);
        }
        As[lc4 + 0][lr] = av.x;
        As[lc4 + 1][lr] = av.y;
        As[lc4 + 2][lr] = av.z;
        As[lc4 + 3][lr] = av.w;
        *(float4*)&Ws[wr][wc4] = *(const float4*)(W + (size_t)(k0 + wr) * N + n0 + wc4);
        __syncthreads();
        #pragma unroll
        for (int kk = 0; kk < 16; ++kk) {
            float4 a4 = *(float4*)&As[kk][tm << 2];
            float4 b4 = *(float4*)&Ws[kk][tn << 2];
            float a[4] = {a4.x, a4.y, a4.z, a4.w};
            float b[4] = {b4.x, b4.y, b4.z, b4.w};
            #pragma unroll
            for (int i = 0; i < 4; ++i)
                #pragma unroll
                for (int j = 0; j < 4; ++j)
                    acc[i][j] += a[i] * b[j];
        }
        __syncthreads();
    }

    #pragma unroll
    for (int i = 0; i < 4; ++i) {
        int m = m0 + (tm << 2) + i;
        #pragma unroll
        for (int j = 0; j < 4; ++j) {
            int n = n0 + (tn << 2) + j;
            float v = acc[i][j];
            if (omode == 0) {
                int l = m / B_, b = m % B_;
                int h = n >> 6, d = n & 63;
                size_t dst = (((size_t)b * H_ + h) * L_ + l) * DH_ + d;
                outA[dst] = v + bu[n];
                outB[dst] = v + bv[n];
            } else if (omode == 1) {
                int t = m / B_, b = m % B_;
                int nn = (n < 1024) ? n : (n - 1024);
                int h = nn >> 6, d = nn & 63;
                size_t dst = (((size_t)b * H_ + h) * T_ + t) * DH_ + d;
                if (n < 1024) outA[dst] = v; else outB[dst] = v;
            } else if (omode == 2) {
                int t = m / B_, b = m % B_;
                int h = n >> 6, d = n & 63;
                outA[(((size_t)b * H_ + h) * T_ + t) * DH_ + d] = v;
            } else {
                outA[(size_t)m * D_ + n] = v + resid[(size_t)m * D_ + n];
            }
        }
    }
}

// ---------------------------------------------------------------------------
// Attention: one block per (16-row q-tile, b*H+h). Full score rows in LDS.
// S[ii][j] = (qu_i . k_j) + (qv_i . r_{j-i+L-1}); softmax over valid j<=i+M;
// attn_matrix += p/32 (atomics); O = p @ V with staged V chunks.
// ---------------------------------------------------------------------------
__global__ __launch_bounds__(256) void attn_kernel(
    const float* __restrict__ qu, const float* __restrict__ qv,
    const float* __restrict__ kbuf, const float* __restrict__ vbuf,
    const float* __restrict__ rbuf,
    float* __restrict__ Ovec, float* __restrict__ AM)
{
    __shared__ float S[16][2048];      // 128 KB
    __shared__ float Qu[16][64];
    __shared__ float Qv[16][64];
    __shared__ float Vs[64][68];       // padded V chunk
    __shared__ float redm[16], redl[16];

    int tid = threadIdx.x;
    int i0 = blockIdx.x * 16;
    int bh = blockIdx.y;
    const float* kp = kbuf + (size_t)bh * T_ * DH_;
    const float* rp = rbuf + (size_t)bh * T_ * DH_;
    const float* vp = vbuf + (size_t)bh * T_ * DH_;

    // stage Q tiles
    {
        int r = tid >> 4;
        int c = (tid & 15) << 2;
        size_t off = (((size_t)bh) * L_ + i0 + r) * DH_ + c;
        *(float4*)&Qu[r][c] = *(const float4*)(qu + off);
        *(float4*)&Qv[r][c] = *(const float4*)(qv + off);
    }
    __syncthreads();

    int jmax_tile = i0 + 15 + M_;               // inclusive max valid j in tile
    int nchunk = (jmax_tile >> 8) + 1;          // 256-col chunks to compute
    if (nchunk > 8) nchunk = 8;

    // ---- AC: thread = one column per chunk ----
    for (int c = 0; c < nchunk; ++c) {
        int j = (c << 8) + tid;
        const float* krow = kp + (size_t)j * DH_;
        float acc[16];
        #pragma unroll
        for (int ii = 0; ii < 16; ++ii) acc[ii] = 0.f;
        #pragma unroll
        for (int d0 = 0; d0 < 64; d0 += 16) {
            float4 kq[4];
            #pragma unroll
            for (int t = 0; t < 4; ++t) kq[t] = *(const float4*)(krow + d0 + (t << 2));
            #pragma unroll
            for (int ii = 0; ii < 16; ++ii) {
                float s = 0.f;
                #pragma unroll
                for (int t = 0; t < 4; ++t) {
                    float4 q4 = *(const float4*)&Qu[ii][d0 + (t << 2)];
                    s += q4.x * kq[t].x + q4.y * kq[t].y + q4.z * kq[t].z + q4.w * kq[t].w;
                }
                acc[ii] += s;
            }
        }
        #pragma unroll
        for (int ii = 0; ii < 16; ++ii) S[ii][j] = acc[ii];
    }
    __syncthreads();

    // ---- BD: thread = one r-row d; scatter along diagonal j = d + i - 1023.
    // Unique writer per (ii,j) since d is determined by (ii,j): no races.
    {
        int dlo = 1008 - i0;                    // 1023 - (i0+15)
        for (int d = dlo + tid; d < T_; d += 256) {
            const float* rrow = rp + (size_t)d * DH_;
            float pacc[16];
            #pragma unroll
            for (int ii = 0; ii < 16; ++ii) pacc[ii] = 0.f;
            #pragma unroll
            for (int d0 = 0; d0 < 64; d0 += 16) {
                float4 rq[4];
                #pragma unroll
                for (int t = 0; t < 4; ++t) rq[t] = *(const float4*)(rrow + d0 + (t << 2));
                #pragma unroll
                for (int ii = 0; ii < 16; ++ii) {
                    float s = 0.f;
                    #pragma unroll
                    for (int t = 0; t < 4; ++t) {
                        float4 q4 = *(const float4*)&Qv[ii][d0 + (t << 2)];
                        s += q4.x * rq[t].x + q4.y * rq[t].y + q4.z * rq[t].z + q4.w * rq[t].w;
                    }
                    pacc[ii] += s;
                }
            }
            #pragma unroll
            for (int ii = 0; ii < 16; ++ii) {
                int j = d + i0 + ii - 1023;
                if (j >= 0 && j < T_) S[ii][j] += pacc[ii];
            }
        }
    }
    __syncthreads();

    // ---- softmax stats: 16 threads per row ----
    {
        int ii = tid >> 4;
        int g = tid & 15;
        int i = i0 + ii;
        int jmax = i + M_;                       // inclusive, <= 2047
        float m = -1e30f;
        for (int j = g; j <= jmax; j += 16) m = fmaxf(m, S[ii][j] * SCALE_);
        #pragma unroll
        for (int o = 8; o > 0; o >>= 1) m = fmaxf(m, __shfl_xor(m, o, 16));
        float l = 0.f;
        for (int j = g; j <= jmax; j += 16) l += __expf(S[ii][j] * SCALE_ - m);
        #pragma unroll
        for (int o = 8; o > 0; o >>= 1) l += __shfl_xor(l, o, 16);
        if (g == 0) { redm[ii] = m; redl[ii] = l; }
    }
    __syncthreads();

    // ---- p = softmax, write attn_matrix contribution ----
    for (int ii = 0; ii < 16; ++ii) {
        int i = i0 + ii;
        int jmax = i + M_;
        float m = redm[ii];
        float linv = 1.f / redl[ii];
        for (int j = tid; j < T_; j += 256) {
            float p = 0.f;
            if (j <= jmax) {
                p = __expf(S[ii][j] * SCALE_ - m) * linv;
                atomicAdd(&AM[(size_t)i * T_ + j], p * 0.03125f);
            }
            S[ii][j] = p;
        }
    }
    __syncthreads();

    // ---- PV: thread = (row iig, 4 cols dd4); staged V chunks of 64 ----
    {
        int iig = tid >> 4;                      // 0..15
        int dd4 = (tid & 15) << 2;               // 0..60
        float4 o4 = {0.f, 0.f, 0.f, 0.f};
        int npv = (jmax_tile >> 6) + 1;
        if (npv > 32) npv = 32;
        for (int c = 0; c < npv; ++c) {
            int base = (c << 6) * DH_;
            #pragma unroll
            for (int t = 0; t < 4; ++t) {
                int idx = (tid << 2) + (t << 10);      // 0..4095
                float4 val = *(const float4*)(vp + base + idx);
                *(float4*)&Vs[idx >> 6][idx & 63] = val;
            }
            __syncthreads();
            int j0 = c << 6;
            #pragma unroll 4
            for (int jj = 0; jj < 64; jj += 4) {
                float4 p4 = *(float4*)&S[iig][j0 + jj];
                float4 v0 = *(float4*)&Vs[jj + 0][dd4];
                float4 v1 = *(float4*)&Vs[jj + 1][dd4];
                float4 v2 = *(float4*)&Vs[jj + 2][dd4];
                float4 v3 = *(float4*)&Vs[jj + 3][dd4];
                o4.x += p4.x * v0.x + p4.y * v1.x + p4.z * v2.x + p4.w * v3.x;
                o4.y += p4.x * v0.y + p4.y * v1.y + p4.z * v2.y + p4.w * v3.y;
                o4.z += p4.x * v0.z + p4.y * v1.z + p4.z * v2.z + p4.w * v3.z;
                o4.w += p4.x * v0.w + p4.y * v1.w + p4.z * v2.w + p4.w * v3.w;
            }
            __syncthreads();
        }
        *(float4*)(Ovec + (((size_t)bh) * L_ + i0 + iig) * DH_ + dd4) = o4;
    }
}

// ---------------------------------------------------------------------------
// LayerNorm over D=1024, one block (256 thr) per row.
// ---------------------------------------------------------------------------
__global__ __launch_bounds__(256) void ln_kernel(
    const float* __restrict__ hbuf,
    const float* __restrict__ gamma, const float* __restrict__ beta,
    float* __restrict__ out)
{
    __shared__ float rs[4], rss[4];
    int row = blockIdx.x;
    int tid = threadIdx.x;
    const float* hp = hbuf + (size_t)row * D_;
    float4 h4 = *(const float4*)(hp + (tid << 2));
    float s = h4.x + h4.y + h4.z + h4.w;
    float ss = h4.x * h4.x + h4.y * h4.y + h4.z * h4.z + h4.w * h4.w;
    #pragma unroll
    for (int o = 32; o > 0; o >>= 1) {
        s  += __shfl_down(s, o);
        ss += __shfl_down(ss, o);
    }
    if ((tid & 63) == 0) { rs[tid >> 6] = s; rss[tid >> 6] = ss; }
    __syncthreads();
    float tot  = rs[0] + rs[1] + rs[2] + rs[3];
    float tots = rss[0] + rss[1] + rss[2] + rss[3];
    float mu = tot * (1.f / D_);
    float var = tots * (1.f / D_) - mu * mu;
    float rstd = rsqrtf(var + 1e-5f);
    float4 g4 = *(const float4*)(gamma + (tid << 2));
    float4 b4 = *(const float4*)(beta + (tid << 2));
    float4 o4;
    o4.x = (h4.x - mu) * rstd * g4.x + b4.x;
    o4.y = (h4.y - mu) * rstd * g4.y + b4.y;
    o4.z = (h4.z - mu) * rstd * g4.z + b4.z;
    o4.w = (h4.w - mu) * rstd * g4.w + b4.w;
    *(float4*)(out + (size_t)row * D_ + (tid << 2)) = o4;
}

extern "C" void kernel_launch(void* const* d_in, const int* in_sizes, int n_in,
                              void* d_out, int out_size, void* d_ws, size_t ws_size,
                              hipStream_t stream) {
    const float* x       = (const float*)d_in[0];
    const float* pos_emb = (const float*)d_in[1];
    const float* memory  = (const float*)d_in[2];
    const float* bu      = (const float*)d_in[3];
    const float* bv      = (const float*)d_in[4];
    // d_in[5] = mask: deterministic (j > i + M), recomputed on device
    const float* Wq      = (const float*)d_in[6];
    const float* Wkv     = (const float*)d_in[7];
    const float* Wrel    = (const float*)d_in[8];
    const float* Wo      = (const float*)d_in[9];
    const float* gamma   = (const float*)d_in[10];
    const float* beta    = (const float*)d_in[11];

    float* out = (float*)d_out;
    float* AM  = out + (size_t)L_ * B_ * D_;     // attn_matrix [L,T]

    float* ws   = (float*)d_ws;
    float* qu   = ws;                            // [B,H,L,DH]  2M floats
    float* qv   = qu   + (size_t)2097152;
    float* kbuf = qv   + (size_t)2097152;        // [B,H,T,DH]  4M
    float* vbuf = kbuf + (size_t)4194304;
    float* rbuf = vbuf + (size_t)4194304;        // [B,H,T,DH]  4M
    float* Ovec = rbuf + (size_t)4194304;        // [B,H,L,DH]  2M
    float* hbuf = Ovec + (size_t)2097152;        // [L*B, D]    2M

    hipMemsetAsync(AM, 0, (size_t)L_ * T_ * sizeof(float), stream);

    dim3 blk(256);
    // q projection (+biases) -> qu, qv
    gemm_proj<<<dim3(32, 16), blk, 0, stream>>>(x, nullptr, 1 << 30, Wq, 1024,
                                                0, 0, bu, bv, qu, qv, nullptr);
    // kv projection on concat(memory, x)
    gemm_proj<<<dim3(64, 32), blk, 0, stream>>>(memory, x, M_ * B_, Wkv, 2048,
                                                0, 1, nullptr, nullptr, kbuf, vbuf, nullptr);
    // r projection
    gemm_proj<<<dim3(64, 16), blk, 0, stream>>>(pos_emb, nullptr, 1 << 30, Wrel, 1024,
                                                0, 2, nullptr, nullptr, rbuf, nullptr, nullptr);
    // attention
    attn_kernel<<<dim3(64, 32), blk, 0, stream>>>(qu, qv, kbuf, vbuf, rbuf, Ovec, AM);
    // output projection + residual
    gemm_proj<<<dim3(32, 16), blk, 0, stream>>>(Ovec, nullptr, 0, Wo, 1024,
                                                1, 3, nullptr, nullptr, hbuf, nullptr, x);
    // layernorm
    ln_kernel<<<2048, blk, 0, stream>>>(hbuf, gamma, beta, out);
}

// Round 2
// 554.290 us; speedup vs baseline: 8.6302x; 8.6302x over previous
//
#include <hip/hip_runtime.h>
#include <math.h>
#include <stdint.h>

#define L_  1024
#define B_  2
#define D_  1024
#define H_  16
#define DH_ 64
#define M_  1024
#define T_  2048
#define SCALE_ 0.125f

typedef unsigned short ushort;
typedef short bf16x8 __attribute__((ext_vector_type(8)));
typedef float f32x4 __attribute__((ext_vector_type(4)));
typedef unsigned short u16x4v __attribute__((ext_vector_type(4)));
typedef unsigned short u16x8v __attribute__((ext_vector_type(8)));

#define MFMA16(a,b,c) __builtin_amdgcn_mfma_f32_16x16x32_bf16(a,b,c,0,0,0)

static __device__ __forceinline__ ushort f2bf(float x) {
    uint32_t u = __float_as_uint(x);
    uint32_t r = (u + 0x7FFFu + ((u >> 16) & 1u)) >> 16;
    return (ushort)r;
}
static __device__ __forceinline__ float bf2f(ushort h) {
    return __uint_as_float(((uint32_t)h) << 16);
}

// ---------------------------------------------------------------------------
// fp32 -> bf16 convert (n multiple of 2048; grid = n/2048, 256 thr)
// ---------------------------------------------------------------------------
__global__ __launch_bounds__(256) void cvt_bf16(const float* __restrict__ src,
                                                ushort* __restrict__ dst, int n) {
    int i = (blockIdx.x * 256 + threadIdx.x) * 8;
    if (i >= n) return;
    float4 a = *(const float4*)(src + i);
    float4 b = *(const float4*)(src + i + 4);
    u16x8v o;
    o[0] = f2bf(a.x); o[1] = f2bf(a.y); o[2] = f2bf(a.z); o[3] = f2bf(a.w);
    o[4] = f2bf(b.x); o[5] = f2bf(b.y); o[6] = f2bf(b.z); o[7] = f2bf(b.w);
    *(u16x8v*)(dst + i) = o;
}

// ---------------------------------------------------------------------------
// fp32 [K][N] -> bf16 [N][K] transpose+convert. 32x32 tiles, 256 thr.
// grid = (K/32, N/32)
// ---------------------------------------------------------------------------
__global__ __launch_bounds__(256) void trans_cvt(const float* __restrict__ src,
                                                 ushort* __restrict__ dst,
                                                 int K, int N) {
    __shared__ float t[32][33];
    int k0 = blockIdx.x * 32, n0 = blockIdx.y * 32;
    int tid = threadIdx.x;
    int r = tid >> 3, c4 = (tid & 7) * 4;
    float4 v = *(const float4*)(src + (size_t)(k0 + r) * N + n0 + c4);
    t[r][c4 + 0] = v.x; t[r][c4 + 1] = v.y; t[r][c4 + 2] = v.z; t[r][c4 + 3] = v.w;
    __syncthreads();
    u16x4v o;
    o[0] = f2bf(t[c4 + 0][r]); o[1] = f2bf(t[c4 + 1][r]);
    o[2] = f2bf(t[c4 + 2][r]); o[3] = f2bf(t[c4 + 3][r]);
    *(u16x4v*)(dst + (size_t)(n0 + r) * K + k0 + c4) = o;
}

// ---------------------------------------------------------------------------
// bf16 MFMA GEMM: C[64x64 tile] = A[M][1024] @ Wt[N][1024]^T
// 256 thr = 4 waves (2x2), wave does 32x32 via 2x2 mfma_16x16x32 tiles.
// omode 0: q -> qu=(+bu), qv=(+bv), layout [bh][L][64] bf16
// omode 1: kv -> n<1024 k else v, layout [bh][T][64] bf16
// omode 2: r -> layout [bh][T][64] bf16
// omode 3: outF[m][n] = acc + resid[m][n]  (fp32)
// ---------------------------------------------------------------------------
__global__ __launch_bounds__(256) void gemm_bf16(
    const ushort* __restrict__ A, const ushort* __restrict__ Wt,
    int omode,
    const float* __restrict__ bu, const float* __restrict__ bv,
    ushort* __restrict__ outA, ushort* __restrict__ outB,
    const float* __restrict__ resid, float* __restrict__ outF)
{
    __shared__ ushort Al[64][40];
    __shared__ ushort Bl[64][40];
    int tid = threadIdx.x;
    int M0 = blockIdx.x * 64, N0 = blockIdx.y * 64;
    int wid = tid >> 6, lane = tid & 63, quad = lane >> 4, jl = lane & 15;
    int m0w = (wid >> 1) * 32, n0w = (wid & 1) * 32;
    int sr = tid >> 2, sc = (tid & 3) * 8;

    f32x4 acc[2][2];
    #pragma unroll
    for (int i = 0; i < 2; ++i)
        #pragma unroll
        for (int j = 0; j < 2; ++j) acc[i][j] = (f32x4){0.f, 0.f, 0.f, 0.f};

    for (int k0 = 0; k0 < 1024; k0 += 32) {
        *(u16x8v*)&Al[sr][sc] = *(const u16x8v*)(A  + (size_t)(M0 + sr) * 1024 + k0 + sc);
        *(u16x8v*)&Bl[sr][sc] = *(const u16x8v*)(Wt + (size_t)(N0 + sr) * 1024 + k0 + sc);
        __syncthreads();
        bf16x8 a0 = *(const bf16x8*)&Al[m0w + jl][quad * 8];
        bf16x8 a1 = *(const bf16x8*)&Al[m0w + 16 + jl][quad * 8];
        bf16x8 b0 = *(const bf16x8*)&Bl[n0w + jl][quad * 8];
        bf16x8 b1 = *(const bf16x8*)&Bl[n0w + 16 + jl][quad * 8];
        acc[0][0] = MFMA16(a0, b0, acc[0][0]);
        acc[0][1] = MFMA16(a0, b1, acc[0][1]);
        acc[1][0] = MFMA16(a1, b0, acc[1][0]);
        acc[1][1] = MFMA16(a1, b1, acc[1][1]);
        __syncthreads();
    }

    #pragma unroll
    for (int ms = 0; ms < 2; ++ms)
        #pragma unroll
        for (int ns = 0; ns < 2; ++ns)
            #pragma unroll
            for (int r = 0; r < 4; ++r) {
                int gm = M0 + m0w + 16 * ms + quad * 4 + r;
                int gn = N0 + n0w + 16 * ns + jl;
                float v = acc[ms][ns][r];
                if (omode == 0) {
                    int l = gm >> 1, b = gm & 1;
                    int h = gn >> 6, d = gn & 63;
                    size_t o = ((size_t)((b << 4) | h) * 1024 + l) * 64 + d;
                    outA[o] = f2bf(v + bu[gn]);
                    outB[o] = f2bf(v + bv[gn]);
                } else if (omode == 1) {
                    int t = gm >> 1, b = gm & 1;
                    int nn = gn & 1023;
                    int h = nn >> 6, d = nn & 63;
                    size_t o = ((size_t)((b << 4) | h) * 2048 + t) * 64 + d;
                    if (gn < 1024) outA[o] = f2bf(v); else outB[o] = f2bf(v);
                } else if (omode == 2) {
                    int t = gm >> 1, b = gm & 1;
                    int h = gn >> 6, d = gn & 63;
                    outA[((size_t)((b << 4) | h) * 2048 + t) * 64 + d] = f2bf(v);
                } else {
                    outF[(size_t)gm * 1024 + gn] = v + resid[(size_t)gm * 1024 + gn];
                }
            }
}

// ---------------------------------------------------------------------------
// Fused attention, two-pass flash. Block = 64 q-rows x one bh; 4 waves, each
// wave owns 16 q-rows. Chunks of 32 keys. BD via shifted-window MFMA + shfl.
// ---------------------------------------------------------------------------
__device__ __forceinline__ void compute_S(
    float s[2][4], const ushort Kl[32][72], const ushort* __restrict__ rp,
    const bf16x8 quA[2], const bf16x8 qvA[2],
    int j0, int i0w, int quad, int jl, int irow)
{
    f32x4 z = (f32x4){0.f, 0.f, 0.f, 0.f};
    f32x4 ac[2];
    #pragma unroll
    for (int su = 0; su < 2; ++su) {
        bf16x8 k0 = *(const bf16x8*)&Kl[su * 16 + jl][quad * 8];
        bf16x8 k1 = *(const bf16x8*)&Kl[su * 16 + jl][32 + quad * 8];
        f32x4 t = MFMA16(quA[0], k0, z);
        ac[su] = MFMA16(quA[1], k1, t);
    }
    // Btmp[ii][c] = qv_i . r[d0 + c], c in [0,47] (3 n-tiles of 16)
    int d0 = 1008 + j0 - i0w;
    f32x4 bt[3];
    #pragma unroll
    for (int nt = 0; nt < 3; ++nt) {
        int rr = d0 + nt * 16 + jl;
        rr = min(max(rr, 0), 2047);
        const ushort* rrow = rp + (size_t)rr * 64;
        bf16x8 r0 = *(const bf16x8*)(rrow + quad * 8);
        bf16x8 r1 = *(const bf16x8*)(rrow + 32 + quad * 8);
        f32x4 t = MFMA16(qvA[0], r0, z);
        bt[nt] = MFMA16(qvA[1], r1, t);
    }
    // extract BD along rel-shift diagonal: c = su*16 + jl + 15 - ii
    #pragma unroll
    for (int su = 0; su < 2; ++su)
        #pragma unroll
        for (int r = 0; r < 4; ++r) {
            int ii = quad * 4 + r;
            int c = su * 16 + jl + 15 - ii;
            int src = (quad << 4) | (c & 15);
            float vlo, vhi;
            if (su == 0) { vlo = __shfl(bt[0][r], src); vhi = __shfl(bt[1][r], src); }
            else         { vlo = __shfl(bt[1][r], src); vhi = __shfl(bt[2][r], src); }
            float bd = (su == 0) ? ((c & 16) ? vhi : vlo)
                                 : ((c & 32) ? vhi : vlo);
            float sv = (ac[su][r] + bd) * SCALE_;
            int i = irow + r;
            int j = j0 + su * 16 + jl;
            s[su][r] = (j <= i + M_) ? sv : -1e30f;
        }
}

__global__ __launch_bounds__(256) void attn_fused(
    const ushort* __restrict__ qu, const ushort* __restrict__ qv,
    const ushort* __restrict__ kb, const ushort* __restrict__ vb,
    const ushort* __restrict__ rb,
    ushort* __restrict__ Ovec, ushort* __restrict__ AMw, float* __restrict__ AM)
{
    __shared__ ushort Kl[32][72];
    __shared__ ushort Vt[64][40];
    __shared__ ushort Pl[4][16][40];

    int tid = threadIdx.x, wid = tid >> 6, lane = tid & 63;
    int quad = lane >> 4, jl = lane & 15;
    int I0 = blockIdx.x * 64;
    int bh = blockIdx.y;
    int i0w = I0 + wid * 16;
    int irow = i0w + quad * 4;

    const ushort* kp  = kb + (size_t)bh * 2048 * 64;
    const ushort* vp  = vb + (size_t)bh * 2048 * 64;
    const ushort* rp  = rb + (size_t)bh * 2048 * 64;
    const ushort* qup = qu + (size_t)bh * 1024 * 64;
    const ushort* qvp = qv + (size_t)bh * 1024 * 64;

    bf16x8 quA[2], qvA[2];
    quA[0] = *(const bf16x8*)(qup + (size_t)(i0w + jl) * 64 + quad * 8);
    quA[1] = *(const bf16x8*)(qup + (size_t)(i0w + jl) * 64 + 32 + quad * 8);
    qvA[0] = *(const bf16x8*)(qvp + (size_t)(i0w + jl) * 64 + quad * 8);
    qvA[1] = *(const bf16x8*)(qvp + (size_t)(i0w + jl) * 64 + 32 + quad * 8);

    int nchunk = (I0 + 63 + M_) / 32 + 1;     // block-uniform
    int str = tid >> 3, stc = (tid & 7) * 8;  // staging: 32 rows x 64 cols

    float mrun[4], lrun[4];
    #pragma unroll
    for (int r = 0; r < 4; ++r) { mrun[r] = -1e30f; lrun[r] = 0.f; }

    // ---------------- pass 1: softmax stats ----------------
    for (int c = 0; c < nchunk; ++c) {
        int j0 = c * 32;
        *(u16x8v*)&Kl[str][stc] = *(const u16x8v*)(kp + (size_t)(j0 + str) * 64 + stc);
        __syncthreads();
        float s[2][4];
        compute_S(s, Kl, rp, quA, qvA, j0, i0w, quad, jl, irow);
        #pragma unroll
        for (int r = 0; r < 4; ++r) {
            float mx = fmaxf(s[0][r], s[1][r]);
            #pragma unroll
            for (int off = 1; off < 16; off <<= 1) mx = fmaxf(mx, __shfl_xor(mx, off));
            float mn = fmaxf(mrun[r], mx);
            float p0 = __expf(s[0][r] - mn);
            float p1 = __expf(s[1][r] - mn);
            float sum = p0 + p1;
            #pragma unroll
            for (int off = 1; off < 16; off <<= 1) sum += __shfl_xor(sum, off);
            lrun[r] = lrun[r] * __expf(mrun[r] - mn) + sum;
            mrun[r] = mn;
        }
        __syncthreads();
    }

    float linv[4];
    #pragma unroll
    for (int r = 0; r < 4; ++r) linv[r] = 1.f / lrun[r];

    // ---------------- pass 2: P, AM, PV ----------------
    f32x4 oacc[4];
    #pragma unroll
    for (int nt = 0; nt < 4; ++nt) oacc[nt] = (f32x4){0.f, 0.f, 0.f, 0.f};

    for (int c = 0; c < nchunk; ++c) {
        int j0 = c * 32;
        *(u16x8v*)&Kl[str][stc] = *(const u16x8v*)(kp + (size_t)(j0 + str) * 64 + stc);
        {
            u16x8v v = *(const u16x8v*)(vp + (size_t)(j0 + str) * 64 + stc);
            #pragma unroll
            for (int e = 0; e < 8; ++e) Vt[stc + e][str] = v[e];
        }
        __syncthreads();
        float s[2][4];
        compute_S(s, Kl, rp, quA, qvA, j0, i0w, quad, jl, irow);
        #pragma unroll
        for (int su = 0; su < 2; ++su)
            #pragma unroll
            for (int r = 0; r < 4; ++r) {
                int i = irow + r;
                int j = j0 + su * 16 + jl;
                float p = __expf(s[su][r] - mrun[r]) * linv[r];
                ushort pb = f2bf(p);
                Pl[wid][quad * 4 + r][su * 16 + jl] = pb;
                if (AMw) {
                    AMw[(size_t)bh * 2097152 + (size_t)i * 2048 + j] = pb;
                } else if (p != 0.f) {
                    atomicAdd(&AM[(size_t)i * 2048 + j], p * 0.03125f);
                }
            }
        __threadfence_block();
        bf16x8 pA = *(const bf16x8*)&Pl[wid][jl][quad * 8];
        #pragma unroll
        for (int nt = 0; nt < 4; ++nt) {
            bf16x8 vB = *(const bf16x8*)&Vt[nt * 16 + jl][quad * 8];
            oacc[nt] = MFMA16(pA, vB, oacc[nt]);
        }
        __syncthreads();
    }

    int b = bh >> 4, h = bh & 15;
    #pragma unroll
    for (int nt = 0; nt < 4; ++nt)
        #pragma unroll
        for (int r = 0; r < 4; ++r) {
            int l = irow + r;
            int d = nt * 16 + jl;
            Ovec[(size_t)(l * 2 + b) * 1024 + h * 64 + d] = f2bf(oacc[nt][r]);
        }
}

// ---------------------------------------------------------------------------
// attn_matrix reduce: AM[i][j] = (1/32) sum_p AMw[p][i][j], masked j>i+M -> 0
// ---------------------------------------------------------------------------
__global__ __launch_bounds__(256) void am_reduce(const ushort* __restrict__ AMw,
                                                 float* __restrict__ AM) {
    size_t idx = ((size_t)blockIdx.x * 256 + threadIdx.x) * 8;
    int i = (int)(idx >> 11);
    int j0 = (int)(idx & 2047);
    float acc[8];
    #pragma unroll
    for (int e = 0; e < 8; ++e) acc[e] = 0.f;
    for (int p = 0; p < 32; ++p) {
        u16x8v v = *(const u16x8v*)(AMw + (size_t)p * 2097152 + idx);
        #pragma unroll
        for (int e = 0; e < 8; ++e) acc[e] += bf2f(v[e]);
    }
    int jmax = i + M_;
    float4 o0, o1;
    o0.x = (j0 + 0 <= jmax) ? acc[0] * 0.03125f : 0.f;
    o0.y = (j0 + 1 <= jmax) ? acc[1] * 0.03125f : 0.f;
    o0.z = (j0 + 2 <= jmax) ? acc[2] * 0.03125f : 0.f;
    o0.w = (j0 + 3 <= jmax) ? acc[3] * 0.03125f : 0.f;
    o1.x = (j0 + 4 <= jmax) ? acc[4] * 0.03125f : 0.f;
    o1.y = (j0 + 5 <= jmax) ? acc[5] * 0.03125f : 0.f;
    o1.z = (j0 + 6 <= jmax) ? acc[6] * 0.03125f : 0.f;
    o1.w = (j0 + 7 <= jmax) ? acc[7] * 0.03125f : 0.f;
    *(float4*)(AM + idx) = o0;
    *(float4*)(AM + idx + 4) = o1;
}

// ---------------------------------------------------------------------------
// LayerNorm over D=1024, one block per row
// ---------------------------------------------------------------------------
__global__ __launch_bounds__(256) void ln_kernel(
    const float* __restrict__ hbuf,
    const float* __restrict__ gamma, const float* __restrict__ beta,
    float* __restrict__ out)
{
    __shared__ float rs[4], rss[4];
    int row = blockIdx.x;
    int tid = threadIdx.x;
    const float* hp = hbuf + (size_t)row * 1024;
    float4 h4 = *(const float4*)(hp + (tid << 2));
    float s = h4.x + h4.y + h4.z + h4.w;
    float ss = h4.x * h4.x + h4.y * h4.y + h4.z * h4.z + h4.w * h4.w;
    #pragma unroll
    for (int o = 32; o > 0; o >>= 1) {
        s  += __shfl_down(s, o);
        ss += __shfl_down(ss, o);
    }
    if ((tid & 63) == 0) { rs[tid >> 6] = s; rss[tid >> 6] = ss; }
    __syncthreads();
    float tot  = rs[0] + rs[1] + rs[2] + rs[3];
    float tots = rss[0] + rss[1] + rss[2] + rss[3];
    float mu = tot * (1.f / 1024.f);
    float var = tots * (1.f / 1024.f) - mu * mu;
    float rstd = rsqrtf(var + 1e-5f);
    float4 g4 = *(const float4*)(gamma + (tid << 2));
    float4 b4 = *(const float4*)(beta + (tid << 2));
    float4 o4;
    o4.x = (h4.x - mu) * rstd * g4.x + b4.x;
    o4.y = (h4.y - mu) * rstd * g4.y + b4.y;
    o4.z = (h4.z - mu) * rstd * g4.z + b4.z;
    o4.w = (h4.w - mu) * rstd * g4.w + b4.w;
    *(float4*)(out + (size_t)row * 1024 + (tid << 2)) = o4;
}

extern "C" void kernel_launch(void* const* d_in, const int* in_sizes, int n_in,
                              void* d_out, int out_size, void* d_ws, size_t ws_size,
                              hipStream_t stream) {
    const float* x       = (const float*)d_in[0];
    const float* pos_emb = (const float*)d_in[1];
    const float* memory  = (const float*)d_in[2];
    const float* bu      = (const float*)d_in[3];
    const float* bv      = (const float*)d_in[4];
    const float* Wq      = (const float*)d_in[6];
    const float* Wkv     = (const float*)d_in[7];
    const float* Wrel    = (const float*)d_in[8];
    const float* Wo      = (const float*)d_in[9];
    const float* gamma   = (const float*)d_in[10];
    const float* beta    = (const float*)d_in[11];

    float* out = (float*)d_out;
    float* AM  = out + (size_t)2097152;   // attn_matrix [L][T]

    ushort* cb    = (ushort*)d_ws;            // [4096][1024] concat(memory,x) bf16
    ushort* pb    = cb    + 4194304;          // [4096][1024]
    ushort* Wqt   = pb    + 4194304;          // [1024][1024]
    ushort* Wkvt  = Wqt   + 1048576;          // [2048][1024]
    ushort* Wrelt = Wkvt  + 2097152;          // [1024][1024]
    ushort* Wot   = Wrelt + 1048576;          // [1024][1024]
    ushort* quB   = Wot   + 1048576;          // [32][1024][64]
    ushort* qvB   = quB   + 2097152;
    ushort* kbB   = qvB   + 2097152;          // [32][2048][64]
    ushort* vbB   = kbB   + 4194304;
    ushort* rbB   = vbB   + 4194304;
    ushort* OvecB = rbB   + 4194304;          // [2048][1024]
    float*  hbuf  = (float*)(OvecB + 2097152);// [2048][1024] fp32
    ushort* AMw   = (ushort*)(hbuf + 2097152);// [32][1024][2048] bf16 (128 MB)

    size_t need = (size_t)65011712 + 8388608 + 134217728; // 207,618,048 B
    bool planes = ws_size >= need;
    ushort* AMw_arg = planes ? AMw : (ushort*)nullptr;

    dim3 blk(256);
    // converts
    cvt_bf16<<<1024, blk, 0, stream>>>(memory, cb, 2097152);
    cvt_bf16<<<1024, blk, 0, stream>>>(x, cb + 2097152, 2097152);
    cvt_bf16<<<2048, blk, 0, stream>>>(pos_emb, pb, 4194304);
    trans_cvt<<<dim3(32, 32), blk, 0, stream>>>(Wq,   Wqt,   1024, 1024);
    trans_cvt<<<dim3(32, 64), blk, 0, stream>>>(Wkv,  Wkvt,  1024, 2048);
    trans_cvt<<<dim3(32, 32), blk, 0, stream>>>(Wrel, Wrelt, 1024, 1024);
    trans_cvt<<<dim3(32, 32), blk, 0, stream>>>(Wo,   Wot,   1024, 1024);
    hipMemsetAsync(AM, 0, (size_t)2097152 * sizeof(float), stream);

    // projections
    gemm_bf16<<<dim3(32, 16), blk, 0, stream>>>(cb + 2097152, Wqt, 0, bu, bv,
                                                quB, qvB, nullptr, nullptr);
    gemm_bf16<<<dim3(64, 32), blk, 0, stream>>>(cb, Wkvt, 1, nullptr, nullptr,
                                                kbB, vbB, nullptr, nullptr);
    gemm_bf16<<<dim3(64, 16), blk, 0, stream>>>(pb, Wrelt, 2, nullptr, nullptr,
                                                rbB, nullptr, nullptr, nullptr);
    // attention
    attn_fused<<<dim3(16, 32), blk, 0, stream>>>(quB, qvB, kbB, vbB, rbB,
                                                 OvecB, AMw_arg, AM);
    // output projection + residual
    gemm_bf16<<<dim3(32, 16), blk, 0, stream>>>(OvecB, Wot, 3, nullptr, nullptr,
                                                nullptr, nullptr, x, hbuf);
    // layernorm
    ln_kernel<<<2048, blk, 0, stream>>>(hbuf, gamma, beta, out);
    // attn_matrix reduction
    if (planes) am_reduce<<<1024, blk, 0, stream>>>(AMw, AM);
}

// Round 3
// 480.514 us; speedup vs baseline: 9.9553x; 1.1535x over previous
//
#include <hip/hip_runtime.h>
#include <math.h>
#include <stdint.h>

#define L_  1024
#define B_  2
#define D_  1024
#define H_  16
#define DH_ 64
#define M_  1024
#define T_  2048
#define SCALE_ 0.125f

typedef unsigned short ushort;
typedef short bf16x8 __attribute__((ext_vector_type(8)));
typedef float f32x4 __attribute__((ext_vector_type(4)));
typedef unsigned short u16x4v __attribute__((ext_vector_type(4)));
typedef unsigned short u16x8v __attribute__((ext_vector_type(8)));

#define MFMA16(a,b,c) __builtin_amdgcn_mfma_f32_16x16x32_bf16(a,b,c,0,0,0)

static __device__ __forceinline__ ushort f2bf(float x) {
    uint32_t u = __float_as_uint(x);
    uint32_t r = (u + 0x7FFFu + ((u >> 16) & 1u)) >> 16;
    return (ushort)r;
}
static __device__ __forceinline__ float bf2f(ushort h) {
    return __uint_as_float(((uint32_t)h) << 16);
}

// ---------------------------------------------------------------------------
// fp32 -> bf16 convert
// ---------------------------------------------------------------------------
__global__ __launch_bounds__(256) void cvt_bf16(const float* __restrict__ src,
                                                ushort* __restrict__ dst, int n) {
    int i = (blockIdx.x * 256 + threadIdx.x) * 8;
    if (i >= n) return;
    float4 a = *(const float4*)(src + i);
    float4 b = *(const float4*)(src + i + 4);
    u16x8v o;
    o[0] = f2bf(a.x); o[1] = f2bf(a.y); o[2] = f2bf(a.z); o[3] = f2bf(a.w);
    o[4] = f2bf(b.x); o[5] = f2bf(b.y); o[6] = f2bf(b.z); o[7] = f2bf(b.w);
    *(u16x8v*)(dst + i) = o;
}

// ---------------------------------------------------------------------------
// fp32 [K][N] -> bf16 [N][K] transpose+convert. 32x32 tiles, 256 thr.
// ---------------------------------------------------------------------------
__global__ __launch_bounds__(256) void trans_cvt(const float* __restrict__ src,
                                                 ushort* __restrict__ dst,
                                                 int K, int N) {
    __shared__ float t[32][33];
    int k0 = blockIdx.x * 32, n0 = blockIdx.y * 32;
    int tid = threadIdx.x;
    int r = tid >> 3, c4 = (tid & 7) * 4;
    float4 v = *(const float4*)(src + (size_t)(k0 + r) * N + n0 + c4);
    t[r][c4 + 0] = v.x; t[r][c4 + 1] = v.y; t[r][c4 + 2] = v.z; t[r][c4 + 3] = v.w;
    __syncthreads();
    u16x4v o;
    o[0] = f2bf(t[c4 + 0][r]); o[1] = f2bf(t[c4 + 1][r]);
    o[2] = f2bf(t[c4 + 2][r]); o[3] = f2bf(t[c4 + 3][r]);
    *(u16x4v*)(dst + (size_t)(n0 + r) * K + k0 + c4) = o;
}

// ---------------------------------------------------------------------------
// bf16 MFMA GEMM: C[64x64] = A[M][1024] @ Wt[N][1024]^T
// omode 0: q -> qu=(+bu), qv=(+bv), layout [bh][L][64]
// omode 1: kv -> n<1024: k row-major [bh][T][64]; else v TRANSPOSED [bh][64][T]
// omode 2: r -> [bh][T][64]
// omode 3: outF[m][n] = acc + resid  (fp32)
// ---------------------------------------------------------------------------
__global__ __launch_bounds__(256) void gemm_bf16(
    const ushort* __restrict__ A, const ushort* __restrict__ Wt,
    int omode,
    const float* __restrict__ bu, const float* __restrict__ bv,
    ushort* __restrict__ outA, ushort* __restrict__ outB,
    const float* __restrict__ resid, float* __restrict__ outF)
{
    __shared__ ushort Al[64][40];
    __shared__ ushort Bl[64][40];
    int tid = threadIdx.x;
    int M0 = blockIdx.x * 64, N0 = blockIdx.y * 64;
    int wid = tid >> 6, lane = tid & 63, quad = lane >> 4, jl = lane & 15;
    int m0w = (wid >> 1) * 32, n0w = (wid & 1) * 32;
    int sr = tid >> 2, sc = (tid & 3) * 8;

    f32x4 acc[2][2];
    #pragma unroll
    for (int i = 0; i < 2; ++i)
        #pragma unroll
        for (int j = 0; j < 2; ++j) acc[i][j] = (f32x4){0.f, 0.f, 0.f, 0.f};

    for (int k0 = 0; k0 < 1024; k0 += 32) {
        *(u16x8v*)&Al[sr][sc] = *(const u16x8v*)(A  + (size_t)(M0 + sr) * 1024 + k0 + sc);
        *(u16x8v*)&Bl[sr][sc] = *(const u16x8v*)(Wt + (size_t)(N0 + sr) * 1024 + k0 + sc);
        __syncthreads();
        bf16x8 a0 = *(const bf16x8*)&Al[m0w + jl][quad * 8];
        bf16x8 a1 = *(const bf16x8*)&Al[m0w + 16 + jl][quad * 8];
        bf16x8 b0 = *(const bf16x8*)&Bl[n0w + jl][quad * 8];
        bf16x8 b1 = *(const bf16x8*)&Bl[n0w + 16 + jl][quad * 8];
        acc[0][0] = MFMA16(a0, b0, acc[0][0]);
        acc[0][1] = MFMA16(a0, b1, acc[0][1]);
        acc[1][0] = MFMA16(a1, b0, acc[1][0]);
        acc[1][1] = MFMA16(a1, b1, acc[1][1]);
        __syncthreads();
    }

    #pragma unroll
    for (int ms = 0; ms < 2; ++ms)
        #pragma unroll
        for (int ns = 0; ns < 2; ++ns)
            #pragma unroll
            for (int r = 0; r < 4; ++r) {
                int gm = M0 + m0w + 16 * ms + quad * 4 + r;
                int gn = N0 + n0w + 16 * ns + jl;
                float v = acc[ms][ns][r];
                if (omode == 0) {
                    int l = gm >> 1, b = gm & 1;
                    int h = gn >> 6, d = gn & 63;
                    size_t o = ((size_t)((b << 4) | h) * 1024 + l) * 64 + d;
                    outA[o] = f2bf(v + bu[gn]);
                    outB[o] = f2bf(v + bv[gn]);
                } else if (omode == 1) {
                    int t = gm >> 1, b = gm & 1;
                    int nn = gn & 1023;
                    int h = nn >> 6, d = nn & 63;
                    if (gn < 1024)
                        outA[((size_t)((b << 4) | h) * 2048 + t) * 64 + d] = f2bf(v);
                    else
                        outB[((size_t)((b << 4) | h) * 64 + d) * 2048 + t] = f2bf(v);
                } else if (omode == 2) {
                    int t = gm >> 1, b = gm & 1;
                    int h = gn >> 6, d = gn & 63;
                    outA[((size_t)((b << 4) | h) * 2048 + t) * 64 + d] = f2bf(v);
                } else {
                    outF[(size_t)gm * 1024 + gn] = v + resid[(size_t)gm * 1024 + gn];
                }
            }
}

// ---------------------------------------------------------------------------
// Barrier-free single-pass attention with j-split.
// Block = 4 independent waves (16 q-rows each) x one bh x one j-segment.
// No-max softmax: p = exp(s), l = sum p; partials combined additively.
// ---------------------------------------------------------------------------
__global__ __launch_bounds__(256) void attn_fused2(
    const ushort* __restrict__ qu, const ushort* __restrict__ qv,
    const ushort* __restrict__ kb, const ushort* __restrict__ Vt,
    const ushort* __restrict__ rb,
    float* __restrict__ Opart, float* __restrict__ lpart,
    ushort* __restrict__ AMw)
{
    __shared__ ushort Pl[4][2][16][40];

    int tid = threadIdx.x, wid = tid >> 6, lane = tid & 63;
    int quad = lane >> 4, jl = lane & 15;
    int I0 = blockIdx.x * 64;
    int bh = blockIdx.y;
    int seg = blockIdx.z;
    int i0w = I0 + wid * 16;
    int irow = i0w + quad * 4;

    const ushort* kp  = kb + (size_t)bh * 2048 * 64;
    const ushort* vtp = Vt + (size_t)bh * 64 * 2048;
    const ushort* rp  = rb + (size_t)bh * 2048 * 64;
    const ushort* qup = qu + (size_t)bh * 1024 * 64;
    const ushort* qvp = qv + (size_t)bh * 1024 * 64;

    bf16x8 quA[2], qvA[2];
    quA[0] = *(const bf16x8*)(qup + (size_t)(i0w + jl) * 64 + quad * 8);
    quA[1] = *(const bf16x8*)(qup + (size_t)(i0w + jl) * 64 + 32 + quad * 8);
    qvA[0] = *(const bf16x8*)(qvp + (size_t)(i0w + jl) * 64 + quad * 8);
    qvA[1] = *(const bf16x8*)(qvp + (size_t)(i0w + jl) * 64 + 32 + quad * 8);

    int nc = (i0w + 1039) / 32 + 1;          // wave-uniform chunk count
    int cb_ = seg ? (nc >> 1) : 0;
    int ce_ = seg ? nc : (nc >> 1);

    f32x4 z = (f32x4){0.f, 0.f, 0.f, 0.f};
    f32x4 oacc[4];
    #pragma unroll
    for (int nt = 0; nt < 4; ++nt) oacc[nt] = z;
    float lsum[4] = {0.f, 0.f, 0.f, 0.f};

    for (int c = cb_; c < ce_; ++c) {
        int j0 = c * 32;
        int par = c & 1;
        // ---- AC ----
        f32x4 ac[2];
        #pragma unroll
        for (int su = 0; su < 2; ++su) {
            const ushort* krow = kp + (size_t)(j0 + su * 16 + jl) * 64;
            bf16x8 k0 = *(const bf16x8*)(krow + quad * 8);
            bf16x8 k1 = *(const bf16x8*)(krow + 32 + quad * 8);
            f32x4 t = MFMA16(quA[0], k0, z);
            ac[su] = MFMA16(quA[1], k1, t);
        }
        // ---- BD windows ----
        int d0 = 1008 + j0 - i0w;
        f32x4 bt[3];
        #pragma unroll
        for (int nt = 0; nt < 3; ++nt) {
            int rr = d0 + nt * 16 + jl;
            rr = min(max(rr, 0), 2047);
            const ushort* rrow = rp + (size_t)rr * 64;
            bf16x8 r0 = *(const bf16x8*)(rrow + quad * 8);
            bf16x8 r1 = *(const bf16x8*)(rrow + 32 + quad * 8);
            f32x4 t = MFMA16(qvA[0], r0, z);
            bt[nt] = MFMA16(qvA[1], r1, t);
        }
        // ---- extract diagonal, exp, stage P ----
        #pragma unroll
        for (int su = 0; su < 2; ++su)
            #pragma unroll
            for (int r = 0; r < 4; ++r) {
                int ii = quad * 4 + r;
                int c2 = su * 16 + jl + 15 - ii;
                int src = (quad << 4) | (c2 & 15);
                float vlo, vhi;
                if (su == 0) { vlo = __shfl(bt[0][r], src); vhi = __shfl(bt[1][r], src); }
                else         { vlo = __shfl(bt[1][r], src); vhi = __shfl(bt[2][r], src); }
                float bd = (su == 0) ? ((c2 & 16) ? vhi : vlo)
                                     : ((c2 & 32) ? vhi : vlo);
                float sv = (ac[su][r] + bd) * SCALE_;
                int i = irow + r;
                int j = j0 + su * 16 + jl;
                float p = (j <= i + M_) ? __expf(fminf(sv, 60.f)) : 0.f;
                lsum[r] += p;
                Pl[wid][par][ii][su * 16 + jl] = f2bf(p);
            }
        asm volatile("s_waitcnt lgkmcnt(0)" ::: "memory");
        bf16x8 pA = *(const bf16x8*)&Pl[wid][par][jl][quad * 8];
        // ---- vectorized plane write (16 rows x 32 cols, 16 B/lane) ----
        {
            int row2 = lane >> 2, col8 = (lane & 3) * 8;
            u16x8v pv = *(const u16x8v*)&Pl[wid][par][row2][col8];
            *(u16x8v*)(AMw + (size_t)bh * 2097152 +
                       (size_t)(i0w + row2) * 2048 + j0 + col8) = pv;
        }
        // ---- PV ----
        #pragma unroll
        for (int nt = 0; nt < 4; ++nt) {
            bf16x8 vB = *(const bf16x8*)(vtp + (size_t)(nt * 16 + jl) * 2048 + j0 + quad * 8);
            oacc[nt] = MFMA16(pA, vB, oacc[nt]);
        }
    }

    // ---- epilogue: combine partials ----
    #pragma unroll
    for (int r = 0; r < 4; ++r) {
        #pragma unroll
        for (int off = 1; off < 16; off <<= 1) lsum[r] += __shfl_xor(lsum[r], off);
        if (jl == 0) atomicAdd(&lpart[(size_t)bh * 1024 + irow + r], lsum[r]);
    }
    #pragma unroll
    for (int nt = 0; nt < 4; ++nt)
        #pragma unroll
        for (int r = 0; r < 4; ++r)
            atomicAdd(&Opart[((size_t)bh * 1024 + irow + r) * 64 + nt * 16 + jl],
                      oacc[nt][r]);
}

// ---------------------------------------------------------------------------
// Combine O partials: O = Opart / l -> bf16 row-major [L*B][1024];
// also emit linvs[bh][i] = (1/l)/32 for am_reduce.
// ---------------------------------------------------------------------------
__global__ __launch_bounds__(256) void o_combine(
    const float* __restrict__ Opart, const float* __restrict__ lpart,
    ushort* __restrict__ OvecB, float* __restrict__ linvs)
{
    int idx8 = (blockIdx.x * 256 + threadIdx.x) * 8;   // over 2M floats
    int bh = idx8 >> 16;
    int rem = idx8 & 65535;
    int i = rem >> 6, d0 = rem & 63;
    float linv = 1.f / lpart[(size_t)bh * 1024 + i];
    float4 a = *(const float4*)(Opart + idx8);
    float4 b4 = *(const float4*)(Opart + idx8 + 4);
    u16x8v o;
    o[0] = f2bf(a.x * linv);  o[1] = f2bf(a.y * linv);
    o[2] = f2bf(a.z * linv);  o[3] = f2bf(a.w * linv);
    o[4] = f2bf(b4.x * linv); o[5] = f2bf(b4.y * linv);
    o[6] = f2bf(b4.z * linv); o[7] = f2bf(b4.w * linv);
    int b = bh >> 4, h = bh & 15;
    *(u16x8v*)(OvecB + (size_t)(i * 2 + b) * 1024 + h * 64 + d0) = o;
    if (d0 == 0) linvs[(size_t)bh * 1024 + i] = linv * 0.03125f;
}

// ---------------------------------------------------------------------------
// AM[i][j] = sum_bh plane[bh][i][j] * linvs[bh][i]   (linvs has /32 folded),
// re-masked. One block per row i.
// ---------------------------------------------------------------------------
__global__ __launch_bounds__(256) void am_reduce(const ushort* __restrict__ AMw,
                                                 const float* __restrict__ linvs,
                                                 float* __restrict__ AM) {
    size_t idx = ((size_t)blockIdx.x * 256 + threadIdx.x) * 8;
    int i = (int)(idx >> 11);
    int j0 = (int)(idx & 2047);
    float acc[8];
    #pragma unroll
    for (int e = 0; e < 8; ++e) acc[e] = 0.f;
    for (int p = 0; p < 32; ++p) {
        float lv = linvs[(size_t)p * 1024 + i];
        u16x8v v = *(const u16x8v*)(AMw + (size_t)p * 2097152 + idx);
        #pragma unroll
        for (int e = 0; e < 8; ++e) acc[e] += bf2f(v[e]) * lv;
    }
    int jmax = i + M_;
    float4 o0, o1;
    o0.x = (j0 + 0 <= jmax) ? acc[0] : 0.f;
    o0.y = (j0 + 1 <= jmax) ? acc[1] : 0.f;
    o0.z = (j0 + 2 <= jmax) ? acc[2] : 0.f;
    o0.w = (j0 + 3 <= jmax) ? acc[3] : 0.f;
    o1.x = (j0 + 4 <= jmax) ? acc[4] : 0.f;
    o1.y = (j0 + 5 <= jmax) ? acc[5] : 0.f;
    o1.z = (j0 + 6 <= jmax) ? acc[6] : 0.f;
    o1.w = (j0 + 7 <= jmax) ? acc[7] : 0.f;
    *(float4*)(AM + idx) = o0;
    *(float4*)(AM + idx + 4) = o1;
}

// ---------------------------------------------------------------------------
// LayerNorm over D=1024, one block per row
// ---------------------------------------------------------------------------
__global__ __launch_bounds__(256) void ln_kernel(
    const float* __restrict__ hbuf,
    const float* __restrict__ gamma, const float* __restrict__ beta,
    float* __restrict__ out)
{
    __shared__ float rs[4], rss[4];
    int row = blockIdx.x;
    int tid = threadIdx.x;
    const float* hp = hbuf + (size_t)row * 1024;
    float4 h4 = *(const float4*)(hp + (tid << 2));
    float s = h4.x + h4.y + h4.z + h4.w;
    float ss = h4.x * h4.x + h4.y * h4.y + h4.z * h4.z + h4.w * h4.w;
    #pragma unroll
    for (int o = 32; o > 0; o >>= 1) {
        s  += __shfl_down(s, o);
        ss += __shfl_down(ss, o);
    }
    if ((tid & 63) == 0) { rs[tid >> 6] = s; rss[tid >> 6] = ss; }
    __syncthreads();
    float tot  = rs[0] + rs[1] + rs[2] + rs[3];
    float tots = rss[0] + rss[1] + rss[2] + rss[3];
    float mu = tot * (1.f / 1024.f);
    float var = tots * (1.f / 1024.f) - mu * mu;
    float rstd = rsqrtf(var + 1e-5f);
    float4 g4 = *(const float4*)(gamma + (tid << 2));
    float4 b4 = *(const float4*)(beta + (tid << 2));
    float4 o4;
    o4.x = (h4.x - mu) * rstd * g4.x + b4.x;
    o4.y = (h4.y - mu) * rstd * g4.y + b4.y;
    o4.z = (h4.z - mu) * rstd * g4.z + b4.z;
    o4.w = (h4.w - mu) * rstd * g4.w + b4.w;
    *(float4*)(out + (size_t)row * 1024 + (tid << 2)) = o4;
}

extern "C" void kernel_launch(void* const* d_in, const int* in_sizes, int n_in,
                              void* d_out, int out_size, void* d_ws, size_t ws_size,
                              hipStream_t stream) {
    const float* x       = (const float*)d_in[0];
    const float* pos_emb = (const float*)d_in[1];
    const float* memory  = (const float*)d_in[2];
    const float* bu      = (const float*)d_in[3];
    const float* bv      = (const float*)d_in[4];
    const float* Wq      = (const float*)d_in[6];
    const float* Wkv     = (const float*)d_in[7];
    const float* Wrel    = (const float*)d_in[8];
    const float* Wo      = (const float*)d_in[9];
    const float* gamma   = (const float*)d_in[10];
    const float* beta    = (const float*)d_in[11];

    float* out = (float*)d_out;
    float* AM  = out + (size_t)2097152;       // attn_matrix [L][T]

    ushort* cb    = (ushort*)d_ws;            // [4096][1024]
    ushort* pb    = cb    + 4194304;          // [4096][1024]
    ushort* Wqt   = pb    + 4194304;          // [1024][1024]
    ushort* Wkvt  = Wqt   + 1048576;          // [2048][1024]
    ushort* Wrelt = Wkvt  + 2097152;          // [1024][1024]
    ushort* Wot   = Wrelt + 1048576;          // [1024][1024]
    ushort* quB   = Wot   + 1048576;          // [32][1024][64]
    ushort* qvB   = quB   + 2097152;
    ushort* kbB   = qvB   + 2097152;          // [32][2048][64]
    ushort* VtB   = kbB   + 4194304;          // [32][64][2048]
    ushort* rbB   = VtB   + 4194304;          // [32][2048][64]
    ushort* OvecB = rbB   + 4194304;          // [2048][1024]
    float*  hbuf  = (float*)(OvecB + 2097152);// [2048][1024] fp32
    float*  Opart = hbuf  + 2097152;          // [32][1024][64] fp32
    float*  lpart = Opart + 2097152;          // [32][1024] fp32
    float*  linvs = lpart + 32768;            // [32][1024] fp32
    ushort* AMw   = (ushort*)(linvs + 32768); // [32][1024][2048] bf16 (128 MB)

    dim3 blk(256);
    // converts
    cvt_bf16<<<1024, blk, 0, stream>>>(memory, cb, 2097152);
    cvt_bf16<<<1024, blk, 0, stream>>>(x, cb + 2097152, 2097152);
    cvt_bf16<<<2048, blk, 0, stream>>>(pos_emb, pb, 4194304);
    trans_cvt<<<dim3(32, 32), blk, 0, stream>>>(Wq,   Wqt,   1024, 1024);
    trans_cvt<<<dim3(32, 64), blk, 0, stream>>>(Wkv,  Wkvt,  1024, 2048);
    trans_cvt<<<dim3(32, 32), blk, 0, stream>>>(Wrel, Wrelt, 1024, 1024);
    trans_cvt<<<dim3(32, 32), blk, 0, stream>>>(Wo,   Wot,   1024, 1024);
    hipMemsetAsync(Opart, 0, (size_t)2097152 * sizeof(float), stream);
    hipMemsetAsync(lpart, 0, (size_t)32768 * sizeof(float), stream);

    // projections
    gemm_bf16<<<dim3(32, 16), blk, 0, stream>>>(cb + 2097152, Wqt, 0, bu, bv,
                                                quB, qvB, nullptr, nullptr);
    gemm_bf16<<<dim3(64, 32), blk, 0, stream>>>(cb, Wkvt, 1, nullptr, nullptr,
                                                kbB, VtB, nullptr, nullptr);
    gemm_bf16<<<dim3(64, 16), blk, 0, stream>>>(pb, Wrelt, 2, nullptr, nullptr,
                                                rbB, nullptr, nullptr, nullptr);
    // attention (barrier-free, j-split x2)
    attn_fused2<<<dim3(16, 32, 2), blk, 0, stream>>>(quB, qvB, kbB, VtB, rbB,
                                                     Opart, lpart, AMw);
    // combine partials -> OvecB + linvs
    o_combine<<<1024, blk, 0, stream>>>(Opart, lpart, OvecB, linvs);
    // output projection + residual
    gemm_bf16<<<dim3(32, 16), blk, 0, stream>>>(OvecB, Wot, 3, nullptr, nullptr,
                                                nullptr, nullptr, x, hbuf);
    // layernorm
    ln_kernel<<<2048, blk, 0, stream>>>(hbuf, gamma, beta, out);
    // attn_matrix reduction
    am_reduce<<<1024, blk, 0, stream>>>(AMw, linvs, AM);
}